// Round 2
// baseline (2511.542 us; speedup 1.0000x reference)
//
#include <hip/hip_runtime.h>

#define N_NODES 100000
#define N_EDGES 1600000
#define IN_DIM  128
#define HID     64
#define CLS     10
#define NLAYER  3
#define BN_EPS  1e-5f

__device__ __forceinline__ float bcast(float v, int lane) {
    return __uint_as_float(__builtin_amdgcn_readlane(__float_as_uint(v), lane));
}

__device__ __forceinline__ int clampi(int v, int lo, int hi) {
    return v < lo ? lo : (v > hi ? hi : v);
}

// ---------- CSR build ----------
__global__ void k_count(const int* __restrict__ ei, int* __restrict__ counts) {
    int e = blockIdx.x * blockDim.x + threadIdx.x;
    if (e < N_EDGES) {
        int d = clampi(ei[N_EDGES + e], 0, N_NODES - 1);   // dst row
        atomicAdd(&counts[d], 1);
    }
}

__global__ void k_scan(const int* __restrict__ counts, int* __restrict__ offsets,
                       int* __restrict__ cursor, float* __restrict__ inv_deg) {
    __shared__ int sums[1024];
    int t = threadIdx.x;
    const int C = (N_NODES + 1023) / 1024;   // 98
    int base = t * C;
    int lim  = base + C; if (lim > N_NODES) lim = N_NODES;
    int s = 0;
    for (int i = base; i < lim; i++) s += counts[i];
    sums[t] = s;
    __syncthreads();
    for (int off = 1; off < 1024; off <<= 1) {
        int v = (t >= off) ? sums[t - off] : 0;
        __syncthreads();
        sums[t] += v;
        __syncthreads();
    }
    int run = (t == 0) ? 0 : sums[t - 1];
    for (int i = base; i < lim; i++) {
        int c = counts[i];
        offsets[i] = run;
        cursor[i]  = run;
        inv_deg[i] = (c > 0) ? 1.0f / (float)c : 0.0f;
        run += c;
    }
    if (t == 1023) offsets[N_NODES] = run;   // == E
}

__global__ void k_scatter(const int* __restrict__ ei, int* __restrict__ cursor,
                          int* __restrict__ ssrc) {
    int e = blockIdx.x * blockDim.x + threadIdx.x;
    if (e < N_EDGES) {
        int d = clampi(ei[N_EDGES + e], 0, N_NODES - 1);
        int s = clampi(ei[e],           0, N_NODES - 1);
        int pos = atomicAdd(&cursor[d], 1);
        if (pos >= 0 && pos < N_EDGES) ssrc[pos] = s;
    }
}

// ---------- fc1: h = relu(x @ W1^T + b1), x [N,128] -> h [N,64] ----------
__global__ __launch_bounds__(256) void k_fc1(const float* __restrict__ x,
                                             const float* __restrict__ w,
                                             const float* __restrict__ b,
                                             float* __restrict__ h) {
    __shared__ float wt[IN_DIM * HID];   // wt[k*64+j] = w[j*128+k], 32 KB
    int t = threadIdx.x;
    for (int i = t; i < IN_DIM * HID; i += 256) {
        int j = i >> 7, k = i & 127;
        wt[k * HID + j] = w[i];
    }
    __syncthreads();
    int wave = (blockIdx.x * 256 + t) >> 6;
    int lane = t & 63;
    int n0 = wave * 8;
    float xa[8], xb[8], acc[8];
#pragma unroll
    for (int m = 0; m < 8; m++) {
        int n = n0 + m;
        bool ok = (n < N_NODES);
        xa[m] = ok ? x[(size_t)n * IN_DIM + lane]      : 0.f;
        xb[m] = ok ? x[(size_t)n * IN_DIM + 64 + lane] : 0.f;
        acc[m] = b[lane];
    }
#pragma unroll
    for (int k = 0; k < 64; k++) {
        float wv = wt[k * HID + lane];
#pragma unroll
        for (int m = 0; m < 8; m++) acc[m] += bcast(xa[m], k) * wv;
    }
#pragma unroll
    for (int k = 0; k < 64; k++) {
        float wv = wt[(64 + k) * HID + lane];
#pragma unroll
        for (int m = 0; m < 8; m++) acc[m] += bcast(xb[m], k) * wv;
    }
#pragma unroll
    for (int m = 0; m < 8; m++) {
        int n = n0 + m;
        if (n < N_NODES) h[(size_t)n * HID + lane] = fmaxf(acc[m], 0.f);
    }
}

// ---------- fused layer: agg = mean(h[nbrs]); hout = agg@Wl^T + bl + h@Wr^T; BN stats ----------
__global__ __launch_bounds__(256) void k_layer(const float* __restrict__ h,
                                               const int* __restrict__ offsets,
                                               const int* __restrict__ ssrc,
                                               const float* __restrict__ inv_deg,
                                               const float* __restrict__ wl,
                                               const float* __restrict__ lb,
                                               const float* __restrict__ wr,
                                               float* __restrict__ hout,
                                               float* __restrict__ stats) {
    __shared__ float wlt[HID * HID];   // 16 KB, wlt[k*64+j] = wl[j*64+k]
    __shared__ float wrt[HID * HID];   // 16 KB
    __shared__ float rsum[4][64], rsq[4][64];
    int t = threadIdx.x;
    for (int i = t; i < HID * HID; i += 256) {
        int j = i >> 6, k = i & 63;
        wlt[k * HID + j] = wl[i];
        wrt[k * HID + j] = wr[i];
    }
    __syncthreads();
    int wave = (blockIdx.x * 256 + t) >> 6;
    int lane = t & 63;
    int n0 = wave * 8;
    float agg[8], hr[8], acc[8];
#pragma unroll
    for (int m = 0; m < 8; m++) {
        int n = n0 + m;
        float a = 0.f, hv = 0.f;
        if (n < N_NODES) {
            int s = offsets[n], e = offsets[n + 1];
            for (int i = s; i < e; i++) {
                int u = ssrc[i];
                a += h[(size_t)u * HID + lane];
            }
            a *= inv_deg[n];
            hv = h[(size_t)n * HID + lane];
        }
        agg[m] = a; hr[m] = hv;
        acc[m] = lb[lane];
    }
#pragma unroll
    for (int k = 0; k < 64; k++) {
        float wlv = wlt[k * HID + lane];
        float wrv = wrt[k * HID + lane];
#pragma unroll
        for (int m = 0; m < 8; m++) {
            acc[m] += bcast(agg[m], k) * wlv;
            acc[m] += bcast(hr[m], k)  * wrv;
        }
    }
    float psum = 0.f, psq = 0.f;
#pragma unroll
    for (int m = 0; m < 8; m++) {
        int n = n0 + m;
        if (n < N_NODES) {
            hout[(size_t)n * HID + lane] = acc[m];
            psum += acc[m];
            psq  += acc[m] * acc[m];
        }
    }
    int w = t >> 6;
    rsum[w][lane] = psum;
    rsq[w][lane]  = psq;
    __syncthreads();
    if (w == 0) {
        float s = rsum[0][lane] + rsum[1][lane] + rsum[2][lane] + rsum[3][lane];
        float q = rsq[0][lane]  + rsq[1][lane]  + rsq[2][lane]  + rsq[3][lane];
        atomicAdd(&stats[lane], s);
        atomicAdd(&stats[HID + lane], q);
    }
}

// ---------- BN + ReLU (in place) ----------
__global__ void k_bnrelu(float* __restrict__ h, const float* __restrict__ stats,
                         const float* __restrict__ gamma, const float* __restrict__ beta) {
    int idx = blockIdx.x * blockDim.x + threadIdx.x;   // over N*HID/4
    if (idx >= N_NODES * HID / 4) return;
    float4 v = ((const float4*)h)[idx];
    int cbase = (idx * 4) & 63;
    float* pv = &v.x;
#pragma unroll
    for (int e = 0; e < 4; e++) {
        int c = cbase + e;
        float mu  = stats[c] * (1.0f / N_NODES);
        float var = stats[HID + c] * (1.0f / N_NODES) - mu * mu;
        float sc  = gamma[c] * rsqrtf(var + BN_EPS);
        float sh  = beta[c] - mu * sc;
        pv[e] = fmaxf(pv[e] * sc + sh, 0.f);
    }
    ((float4*)h)[idx] = v;
}

// ---------- fc2 + log_softmax ----------
__global__ __launch_bounds__(256) void k_fc2(const float* __restrict__ h,
                                             const float* __restrict__ w2,
                                             const float* __restrict__ b2,
                                             float* __restrict__ out) {
    __shared__ float w[CLS * HID];
    int t = threadIdx.x;
    for (int i = t; i < CLS * HID; i += 256) w[i] = w2[i];
    __syncthreads();
    int n = (blockIdx.x * 256 + t) >> 6;
    int lane = t & 63;
    if (n >= N_NODES) return;
    float hv = h[(size_t)n * HID + lane];
    float logit[CLS];
#pragma unroll
    for (int j = 0; j < CLS; j++) {
        float p = hv * w[j * HID + lane];
#pragma unroll
        for (int off = 32; off > 0; off >>= 1) p += __shfl_xor(p, off);
        logit[j] = p + b2[j];
    }
    float mx = logit[0];
#pragma unroll
    for (int j = 1; j < CLS; j++) mx = fmaxf(mx, logit[j]);
    float se = 0.f;
#pragma unroll
    for (int j = 0; j < CLS; j++) se += __expf(logit[j] - mx);
    float lse = mx + __logf(se);
    if (lane < CLS) {
        float v = logit[0];
#pragma unroll
        for (int j = 1; j < CLS; j++) v = (lane == j) ? logit[j] : v;
        out[(size_t)n * CLS + lane] = v - lse;
    }
}

extern "C" void kernel_launch(void* const* d_in, const int* in_sizes, int n_in,
                              void* d_out, int out_size, void* d_ws, size_t ws_size,
                              hipStream_t stream) {
    const float* x        = (const float*)d_in[0];
    const int*   ei       = (const int*)d_in[1];     // int32: [2, E] flat
    const float* fc1_w    = (const float*)d_in[2];
    const float* fc1_b    = (const float*)d_in[3];
    const float* lin_l_w  = (const float*)d_in[4];
    const float* lin_l_b  = (const float*)d_in[5];
    const float* lin_r_w  = (const float*)d_in[6];
    const float* bn_gamma = (const float*)d_in[7];
    const float* bn_beta  = (const float*)d_in[8];
    const float* fc2_w    = (const float*)d_in[9];
    const float* fc2_b    = (const float*)d_in[10];
    float* out = (float*)d_out;

    char* p = (char*)d_ws;
    float* h0      = (float*)p; p += (size_t)N_NODES * HID * 4;
    float* h1      = (float*)p; p += (size_t)N_NODES * HID * 4;
    int*   counts  = (int*)p;   p += (size_t)N_NODES * 4;      // reused as nothing after scan
    int*   offsets = (int*)p;   p += (size_t)(N_NODES + 1) * 4;
    int*   cursor  = (int*)p;   p += (size_t)N_NODES * 4;
    int*   ssrc    = (int*)p;   p += (size_t)N_EDGES * 4;
    float* inv_deg = (float*)p; p += (size_t)N_NODES * 4;
    float* stats   = (float*)p; p += 2 * HID * 4;

    hipMemsetAsync(counts, 0, (size_t)N_NODES * 4, stream);
    k_count  <<<(N_EDGES + 255) / 256, 256, 0, stream>>>(ei, counts);
    k_scan   <<<1, 1024, 0, stream>>>(counts, offsets, cursor, inv_deg);
    k_scatter<<<(N_EDGES + 255) / 256, 256, 0, stream>>>(ei, cursor, ssrc);
    k_fc1    <<<3125, 256, 0, stream>>>(x, fc1_w, fc1_b, h0);

    float* hc = h0; float* hn = h1;
    for (int l = 0; l < NLAYER; l++) {
        hipMemsetAsync(stats, 0, 2 * HID * 4, stream);
        k_layer<<<3125, 256, 0, stream>>>(hc, offsets, ssrc, inv_deg,
                                          lin_l_w + (size_t)l * HID * HID,
                                          lin_l_b + (size_t)l * HID,
                                          lin_r_w + (size_t)l * HID * HID,
                                          hn, stats);
        k_bnrelu<<<(N_NODES * HID / 4 + 255) / 256, 256, 0, stream>>>(
            hn, stats, bn_gamma + (size_t)l * HID, bn_beta + (size_t)l * HID);
        float* tmp = hc; hc = hn; hn = tmp;
    }
    k_fc2<<<25000, 256, 0, stream>>>(hc, fc2_w, fc2_b, out);
}

// Round 3
// 1632.496 us; speedup vs baseline: 1.5385x; 1.5385x over previous
//
#include <hip/hip_runtime.h>

#define N_NODES 100000
#define N_EDGES 1600000
#define IN_DIM  128
#define HID     64
#define CLS     10
#define NLAYER  3
#define BN_EPS  1e-5f

__device__ __forceinline__ float bcast(float v, int lane) {
    return __uint_as_float(__builtin_amdgcn_readlane(__float_as_uint(v), lane));
}

__device__ __forceinline__ int clampi(int v, int lo, int hi) {
    return v < lo ? lo : (v > hi ? hi : v);
}

// ---------- CSR build ----------
__global__ void k_count(const int* __restrict__ ei, int* __restrict__ counts) {
    int e = blockIdx.x * blockDim.x + threadIdx.x;
    if (e < N_EDGES) {
        int d = clampi(ei[N_EDGES + e], 0, N_NODES - 1);   // dst row
        atomicAdd(&counts[d], 1);
    }
}

__global__ void k_scan(const int* __restrict__ counts, int* __restrict__ offsets,
                       int* __restrict__ cursor, float* __restrict__ inv_deg) {
    __shared__ int sums[1024];
    int t = threadIdx.x;
    const int C = (N_NODES + 1023) / 1024;   // 98
    int base = t * C;
    int lim  = base + C; if (lim > N_NODES) lim = N_NODES;
    int s = 0;
    for (int i = base; i < lim; i++) s += counts[i];
    sums[t] = s;
    __syncthreads();
    for (int off = 1; off < 1024; off <<= 1) {
        int v = (t >= off) ? sums[t - off] : 0;
        __syncthreads();
        sums[t] += v;
        __syncthreads();
    }
    int run = (t == 0) ? 0 : sums[t - 1];
    for (int i = base; i < lim; i++) {
        int c = counts[i];
        offsets[i] = run;
        cursor[i]  = run;
        inv_deg[i] = (c > 0) ? 1.0f / (float)c : 0.0f;
        run += c;
    }
    if (t == 1023) offsets[N_NODES] = run;   // == E
}

__global__ void k_scatter(const int* __restrict__ ei, int* __restrict__ cursor,
                          int* __restrict__ ssrc) {
    int e = blockIdx.x * blockDim.x + threadIdx.x;
    if (e < N_EDGES) {
        int d = clampi(ei[N_EDGES + e], 0, N_NODES - 1);
        int s = clampi(ei[e],           0, N_NODES - 1);
        int pos = atomicAdd(&cursor[d], 1);
        if (pos >= 0 && pos < N_EDGES) ssrc[pos] = s;
    }
}

// ---------- fc1: h = relu(x @ W1^T + b1), x [N,128] -> h [N,64] ----------
__global__ __launch_bounds__(256) void k_fc1(const float* __restrict__ x,
                                             const float* __restrict__ w,
                                             const float* __restrict__ b,
                                             float* __restrict__ h) {
    __shared__ float wt[IN_DIM * 65];   // wt[k*65+j] = w[j*128+k], padded stride
    int t = threadIdx.x;
    for (int i = t; i < IN_DIM * HID; i += 256) {
        int j = i >> 7, k = i & 127;
        wt[k * 65 + j] = w[i];
    }
    __syncthreads();
    int wave = (blockIdx.x * 256 + t) >> 6;
    int lane = t & 63;
    int n0 = wave * 8;
    float xa[8], xb[8], acc[8];
#pragma unroll
    for (int m = 0; m < 8; m++) {
        int n = n0 + m;
        bool ok = (n < N_NODES);
        xa[m] = ok ? x[(size_t)n * IN_DIM + lane]      : 0.f;
        xb[m] = ok ? x[(size_t)n * IN_DIM + 64 + lane] : 0.f;
        acc[m] = b[lane];
    }
#pragma unroll
    for (int k = 0; k < 64; k++) {
        float wv = wt[k * 65 + lane];
#pragma unroll
        for (int m = 0; m < 8; m++) acc[m] += bcast(xa[m], k) * wv;
    }
#pragma unroll
    for (int k = 0; k < 64; k++) {
        float wv = wt[(64 + k) * 65 + lane];
#pragma unroll
        for (int m = 0; m < 8; m++) acc[m] += bcast(xb[m], k) * wv;
    }
#pragma unroll
    for (int m = 0; m < 8; m++) {
        int n = n0 + m;
        if (n < N_NODES) h[(size_t)n * HID + lane] = fmaxf(acc[m], 0.f);
    }
}

// ---------- fused layer: agg = mean(h[nbrs]); hout = agg@Wl^T + bl + h@Wr^T; BN stats ----------
__global__ __launch_bounds__(256) void k_layer(const float* __restrict__ h,
                                               const int* __restrict__ offsets,
                                               const int* __restrict__ ssrc,
                                               const float* __restrict__ inv_deg,
                                               const float* __restrict__ wl,
                                               const float* __restrict__ lb,
                                               const float* __restrict__ wr,
                                               float* __restrict__ hout,
                                               float* __restrict__ stats) {
    __shared__ float wlt[HID * 65];   // wlt[k*65+j] = wl[j*64+k], padded stride
    __shared__ float wrt[HID * 65];
    __shared__ float rsum[4][64], rsq[4][64];
    int t = threadIdx.x;
    for (int i = t; i < HID * HID; i += 256) {
        int j = i >> 6, k = i & 63;
        wlt[k * 65 + j] = wl[i];
        wrt[k * 65 + j] = wr[i];
    }
    __syncthreads();
    int wave = (blockIdx.x * 256 + t) >> 6;
    int lane = t & 63;
    int n0 = wave * 8;
    float agg[8], hr[8], acc[8];
#pragma unroll
    for (int m = 0; m < 8; m++) {
        int n = n0 + m;
        float a = 0.f, hv = 0.f;
        if (n < N_NODES) {
            int s = offsets[n], e = offsets[n + 1];
            int i = s;
            // 8-deep unrolled gather: 8 independent row-loads in flight
            for (; i + 8 <= e; i += 8) {
                int u0 = ssrc[i + 0], u1 = ssrc[i + 1], u2 = ssrc[i + 2], u3 = ssrc[i + 3];
                int u4 = ssrc[i + 4], u5 = ssrc[i + 5], u6 = ssrc[i + 6], u7 = ssrc[i + 7];
                float v0 = h[(size_t)u0 * HID + lane];
                float v1 = h[(size_t)u1 * HID + lane];
                float v2 = h[(size_t)u2 * HID + lane];
                float v3 = h[(size_t)u3 * HID + lane];
                float v4 = h[(size_t)u4 * HID + lane];
                float v5 = h[(size_t)u5 * HID + lane];
                float v6 = h[(size_t)u6 * HID + lane];
                float v7 = h[(size_t)u7 * HID + lane];
                a += ((v0 + v1) + (v2 + v3)) + ((v4 + v5) + (v6 + v7));
            }
            for (; i < e; i++) {
                int u = ssrc[i];
                a += h[(size_t)u * HID + lane];
            }
            a *= inv_deg[n];
            hv = h[(size_t)n * HID + lane];
        }
        agg[m] = a; hr[m] = hv;
        acc[m] = lb[lane];
    }
#pragma unroll
    for (int k = 0; k < 64; k++) {
        float wlv = wlt[k * 65 + lane];
        float wrv = wrt[k * 65 + lane];
#pragma unroll
        for (int m = 0; m < 8; m++) {
            acc[m] += bcast(agg[m], k) * wlv;
            acc[m] += bcast(hr[m], k)  * wrv;
        }
    }
    float psum = 0.f, psq = 0.f;
#pragma unroll
    for (int m = 0; m < 8; m++) {
        int n = n0 + m;
        if (n < N_NODES) {
            hout[(size_t)n * HID + lane] = acc[m];
            psum += acc[m];
            psq  += acc[m] * acc[m];
        }
    }
    int w = t >> 6;
    rsum[w][lane] = psum;
    rsq[w][lane]  = psq;
    __syncthreads();
    if (w == 0) {
        float s = rsum[0][lane] + rsum[1][lane] + rsum[2][lane] + rsum[3][lane];
        float q = rsq[0][lane]  + rsq[1][lane]  + rsq[2][lane]  + rsq[3][lane];
        atomicAdd(&stats[lane], s);
        atomicAdd(&stats[HID + lane], q);
    }
}

// ---------- BN + ReLU (in place) ----------
__global__ void k_bnrelu(float* __restrict__ h, const float* __restrict__ stats,
                         const float* __restrict__ gamma, const float* __restrict__ beta) {
    int idx = blockIdx.x * blockDim.x + threadIdx.x;   // over N*HID/4
    if (idx >= N_NODES * HID / 4) return;
    float4 v = ((const float4*)h)[idx];
    int cbase = (idx * 4) & 63;
    float* pv = &v.x;
#pragma unroll
    for (int e = 0; e < 4; e++) {
        int c = cbase + e;
        float mu  = stats[c] * (1.0f / N_NODES);
        float var = stats[HID + c] * (1.0f / N_NODES) - mu * mu;
        float sc  = gamma[c] * rsqrtf(var + BN_EPS);
        float sh  = beta[c] - mu * sc;
        pv[e] = fmaxf(pv[e] * sc + sh, 0.f);
    }
    ((float4*)h)[idx] = v;
}

// ---------- fc2 + log_softmax ----------
__global__ __launch_bounds__(256) void k_fc2(const float* __restrict__ h,
                                             const float* __restrict__ w2,
                                             const float* __restrict__ b2,
                                             float* __restrict__ out) {
    __shared__ float w[CLS * HID];
    int t = threadIdx.x;
    for (int i = t; i < CLS * HID; i += 256) w[i] = w2[i];
    __syncthreads();
    int n = (blockIdx.x * 256 + t) >> 6;
    int lane = t & 63;
    if (n >= N_NODES) return;
    float hv = h[(size_t)n * HID + lane];
    float logit[CLS];
#pragma unroll
    for (int j = 0; j < CLS; j++) {
        float p = hv * w[j * HID + lane];
#pragma unroll
        for (int off = 32; off > 0; off >>= 1) p += __shfl_xor(p, off);
        logit[j] = p + b2[j];
    }
    float mx = logit[0];
#pragma unroll
    for (int j = 1; j < CLS; j++) mx = fmaxf(mx, logit[j]);
    float se = 0.f;
#pragma unroll
    for (int j = 0; j < CLS; j++) se += __expf(logit[j] - mx);
    float lse = mx + __logf(se);
    if (lane < CLS) {
        float v = logit[0];
#pragma unroll
        for (int j = 1; j < CLS; j++) v = (lane == j) ? logit[j] : v;
        out[(size_t)n * CLS + lane] = v - lse;
    }
}

extern "C" void kernel_launch(void* const* d_in, const int* in_sizes, int n_in,
                              void* d_out, int out_size, void* d_ws, size_t ws_size,
                              hipStream_t stream) {
    const float* x        = (const float*)d_in[0];
    const int*   ei       = (const int*)d_in[1];     // int32: [2, E] flat
    const float* fc1_w    = (const float*)d_in[2];
    const float* fc1_b    = (const float*)d_in[3];
    const float* lin_l_w  = (const float*)d_in[4];
    const float* lin_l_b  = (const float*)d_in[5];
    const float* lin_r_w  = (const float*)d_in[6];
    const float* bn_gamma = (const float*)d_in[7];
    const float* bn_beta  = (const float*)d_in[8];
    const float* fc2_w    = (const float*)d_in[9];
    const float* fc2_b    = (const float*)d_in[10];
    float* out = (float*)d_out;

    char* p = (char*)d_ws;
    float* h0      = (float*)p; p += (size_t)N_NODES * HID * 4;
    float* h1      = (float*)p; p += (size_t)N_NODES * HID * 4;
    int*   counts  = (int*)p;   p += (size_t)N_NODES * 4;
    int*   offsets = (int*)p;   p += (size_t)(N_NODES + 1) * 4;
    int*   cursor  = (int*)p;   p += (size_t)N_NODES * 4;
    int*   ssrc    = (int*)p;   p += (size_t)N_EDGES * 4;
    float* inv_deg = (float*)p; p += (size_t)N_NODES * 4;
    float* stats   = (float*)p; p += 2 * HID * 4;

    hipMemsetAsync(counts, 0, (size_t)N_NODES * 4, stream);
    k_count  <<<(N_EDGES + 255) / 256, 256, 0, stream>>>(ei, counts);
    k_scan   <<<1, 1024, 0, stream>>>(counts, offsets, cursor, inv_deg);
    k_scatter<<<(N_EDGES + 255) / 256, 256, 0, stream>>>(ei, cursor, ssrc);
    k_fc1    <<<3125, 256, 0, stream>>>(x, fc1_w, fc1_b, h0);

    float* hc = h0; float* hn = h1;
    for (int l = 0; l < NLAYER; l++) {
        hipMemsetAsync(stats, 0, 2 * HID * 4, stream);
        k_layer<<<3125, 256, 0, stream>>>(hc, offsets, ssrc, inv_deg,
                                          lin_l_w + (size_t)l * HID * HID,
                                          lin_l_b + (size_t)l * HID,
                                          lin_r_w + (size_t)l * HID * HID,
                                          hn, stats);
        k_bnrelu<<<(N_NODES * HID / 4 + 255) / 256, 256, 0, stream>>>(
            hn, stats, bn_gamma + (size_t)l * HID, bn_beta + (size_t)l * HID);
        float* tmp = hc; hc = hn; hn = tmp;
    }
    k_fc2<<<25000, 256, 0, stream>>>(hc, fc2_w, fc2_b, out);
}

// Round 4
// 1317.254 us; speedup vs baseline: 1.9066x; 1.2393x over previous
//
#include <hip/hip_runtime.h>

#define N_NODES 100000
#define N_EDGES 1600000
#define IN_DIM  128
#define HID     64
#define CLS     10
#define NLAYER  3
#define BN_EPS  1e-5f
#define INV_N   (1.0f / N_NODES)

__device__ __forceinline__ float bcast(float v, int lane) {
    return __uint_as_float(__builtin_amdgcn_readlane(__float_as_uint(v), lane));
}

__device__ __forceinline__ int clampi(int v, int lo, int hi) {
    return v < lo ? lo : (v > hi ? hi : v);
}

// ---------- CSR build ----------
__global__ void k_count(const int* __restrict__ ei, int* __restrict__ counts) {
    int e = blockIdx.x * blockDim.x + threadIdx.x;
    if (e < N_EDGES) {
        int d = clampi(ei[N_EDGES + e], 0, N_NODES - 1);   // dst row
        atomicAdd(&counts[d], 1);
    }
}

__global__ void k_scan(const int* __restrict__ counts, int* __restrict__ offsets,
                       int* __restrict__ cursor, float* __restrict__ inv_deg) {
    __shared__ int sums[1024];
    int t = threadIdx.x;
    const int C = (N_NODES + 1023) / 1024;   // 98
    int base = t * C;
    int lim  = base + C; if (lim > N_NODES) lim = N_NODES;
    int s = 0;
    for (int i = base; i < lim; i++) s += counts[i];
    sums[t] = s;
    __syncthreads();
    for (int off = 1; off < 1024; off <<= 1) {
        int v = (t >= off) ? sums[t - off] : 0;
        __syncthreads();
        sums[t] += v;
        __syncthreads();
    }
    int run = (t == 0) ? 0 : sums[t - 1];
    for (int i = base; i < lim; i++) {
        int c = counts[i];
        offsets[i] = run;
        cursor[i]  = run;
        inv_deg[i] = (c > 0) ? 1.0f / (float)c : 0.0f;
        run += c;
    }
    if (t == 1023) offsets[N_NODES] = run;   // == E
}

__global__ void k_scatter(const int* __restrict__ ei, int* __restrict__ cursor,
                          int* __restrict__ ssrc) {
    int e = blockIdx.x * blockDim.x + threadIdx.x;
    if (e < N_EDGES) {
        int d = clampi(ei[N_EDGES + e], 0, N_NODES - 1);
        int s = clampi(ei[e],           0, N_NODES - 1);
        int pos = atomicAdd(&cursor[d], 1);
        if (pos >= 0 && pos < N_EDGES) ssrc[pos] = s;
    }
}

// ---------- fc1: h = relu(x @ W1^T + b1), x [N,128] -> h [N,64] ----------
__global__ __launch_bounds__(256) void k_fc1(const float* __restrict__ x,
                                             const float* __restrict__ w,
                                             const float* __restrict__ b,
                                             float* __restrict__ h) {
    __shared__ float wt[IN_DIM * 65];   // wt[k*65+j] = w[j*128+k], padded stride
    int t = threadIdx.x;
    for (int i = t; i < IN_DIM * HID; i += 256) {
        int j = i >> 7, k = i & 127;
        wt[k * 65 + j] = w[i];
    }
    __syncthreads();
    int wave = (blockIdx.x * 256 + t) >> 6;
    int lane = t & 63;
    int n0 = wave * 8;
    float xa[8], xb[8], acc[8];
#pragma unroll
    for (int m = 0; m < 8; m++) {
        int n = n0 + m;
        bool ok = (n < N_NODES);
        xa[m] = ok ? x[(size_t)n * IN_DIM + lane]      : 0.f;
        xb[m] = ok ? x[(size_t)n * IN_DIM + 64 + lane] : 0.f;
        acc[m] = b[lane];
    }
#pragma unroll
    for (int k = 0; k < 64; k++) {
        float wv = wt[k * 65 + lane];
#pragma unroll
        for (int m = 0; m < 8; m++) acc[m] += bcast(xa[m], k) * wv;
    }
#pragma unroll
    for (int k = 0; k < 64; k++) {
        float wv = wt[(64 + k) * 65 + lane];
#pragma unroll
        for (int m = 0; m < 8; m++) acc[m] += bcast(xb[m], k) * wv;
    }
#pragma unroll
    for (int m = 0; m < 8; m++) {
        int n = n0 + m;
        if (n < N_NODES) h[(size_t)n * HID + lane] = fmaxf(acc[m], 0.f);
    }
}

// ---------- k_agg: agg[n] = mean_{u in nbrs(n)} f(hin[u]) ----------
// f = BN+ReLU (from raw sum/sumsq stats) if use_bn, else identity.
// One wave per node; 4 groups of 16 lanes; lane holds float4 (4 channels).
// Group g takes neighbor slots s+g, s+g+4, ... ; unroll 4 -> 16 rows in flight.
__global__ __launch_bounds__(256, 6) void k_agg(const float* __restrict__ hin,
                                                const int* __restrict__ offsets,
                                                const int* __restrict__ ssrc,
                                                const float* __restrict__ inv_deg,
                                                const float* __restrict__ stats,
                                                const float* __restrict__ gamma,
                                                const float* __restrict__ beta,
                                                int use_bn,
                                                float* __restrict__ aggout) {
    int wave = (blockIdx.x * 256 + threadIdx.x) >> 6;
    int lane = threadIdx.x & 63;
    int g  = lane >> 4;       // group 0..3
    int gl = lane & 15;       // lane within group; channels gl*4 .. gl*4+3
    int n = wave;
    if (n >= N_NODES) return;

    float sc0 = 1.f, sc1 = 1.f, sc2 = 1.f, sc3 = 1.f;
    float sh0 = 0.f, sh1 = 0.f, sh2 = 0.f, sh3 = 0.f;
    if (use_bn) {
        int c = gl * 4;
        float4 s1 = *(const float4*)&stats[c];
        float4 s2 = *(const float4*)&stats[HID + c];
        float4 ga = *(const float4*)&gamma[c];
        float4 be = *(const float4*)&beta[c];
        float mu, var;
        mu = s1.x * INV_N; var = s2.x * INV_N - mu * mu; sc0 = ga.x * rsqrtf(var + BN_EPS); sh0 = be.x - mu * sc0;
        mu = s1.y * INV_N; var = s2.y * INV_N - mu * mu; sc1 = ga.y * rsqrtf(var + BN_EPS); sh1 = be.y - mu * sc1;
        mu = s1.z * INV_N; var = s2.z * INV_N - mu * mu; sc2 = ga.z * rsqrtf(var + BN_EPS); sh2 = be.z - mu * sc2;
        mu = s1.w * INV_N; var = s2.w * INV_N - mu * mu; sc3 = ga.w * rsqrtf(var + BN_EPS); sh3 = be.w - mu * sc3;
    }

    int s = offsets[n], e = offsets[n + 1];
    float ax = 0.f, ay = 0.f, az = 0.f, aw = 0.f;
    int i = s + g;

#define GATHER1(u) do { \
        const float4 v = *(const float4*)&hin[(size_t)(u) * HID + gl * 4]; \
        if (use_bn) { \
            ax += fmaxf(v.x * sc0 + sh0, 0.f); \
            ay += fmaxf(v.y * sc1 + sh1, 0.f); \
            az += fmaxf(v.z * sc2 + sh2, 0.f); \
            aw += fmaxf(v.w * sc3 + sh3, 0.f); \
        } else { ax += v.x; ay += v.y; az += v.z; aw += v.w; } \
    } while (0)

    for (; i + 12 < e; i += 16) {
        int u0 = ssrc[i], u1 = ssrc[i + 4], u2 = ssrc[i + 8], u3 = ssrc[i + 12];
        const float4 v0 = *(const float4*)&hin[(size_t)u0 * HID + gl * 4];
        const float4 v1 = *(const float4*)&hin[(size_t)u1 * HID + gl * 4];
        const float4 v2 = *(const float4*)&hin[(size_t)u2 * HID + gl * 4];
        const float4 v3 = *(const float4*)&hin[(size_t)u3 * HID + gl * 4];
        if (use_bn) {
            ax += fmaxf(v0.x * sc0 + sh0, 0.f) + fmaxf(v1.x * sc0 + sh0, 0.f)
                + fmaxf(v2.x * sc0 + sh0, 0.f) + fmaxf(v3.x * sc0 + sh0, 0.f);
            ay += fmaxf(v0.y * sc1 + sh1, 0.f) + fmaxf(v1.y * sc1 + sh1, 0.f)
                + fmaxf(v2.y * sc1 + sh1, 0.f) + fmaxf(v3.y * sc1 + sh1, 0.f);
            az += fmaxf(v0.z * sc2 + sh2, 0.f) + fmaxf(v1.z * sc2 + sh2, 0.f)
                + fmaxf(v2.z * sc2 + sh2, 0.f) + fmaxf(v3.z * sc2 + sh2, 0.f);
            aw += fmaxf(v0.w * sc3 + sh3, 0.f) + fmaxf(v1.w * sc3 + sh3, 0.f)
                + fmaxf(v2.w * sc3 + sh3, 0.f) + fmaxf(v3.w * sc3 + sh3, 0.f);
        } else {
            ax += (v0.x + v1.x) + (v2.x + v3.x);
            ay += (v0.y + v1.y) + (v2.y + v3.y);
            az += (v0.z + v1.z) + (v2.z + v3.z);
            aw += (v0.w + v1.w) + (v2.w + v3.w);
        }
    }
    for (; i < e; i += 4) {
        int u = ssrc[i];
        GATHER1(u);
    }
#undef GATHER1

    // cross-group reduce (lanes gl, gl+16, gl+32, gl+48)
#pragma unroll
    for (int st = 16; st <= 32; st <<= 1) {
        ax += __shfl_xor(ax, st);
        ay += __shfl_xor(ay, st);
        az += __shfl_xor(az, st);
        aw += __shfl_xor(aw, st);
    }
    if (g == 0) {
        float id = inv_deg[n];
        float4 r; r.x = ax * id; r.y = ay * id; r.z = az * id; r.w = aw * id;
        *(float4*)&aggout[(size_t)n * HID + gl * 4] = r;
    }
}

// ---------- k_gemm: pre[n] = Wl*agg[n] + bl + Wr*f(hself[n]); BN stats of pre ----------
// Writes pre IN PLACE over agg. f = BN+ReLU if use_bn else identity.
__global__ __launch_bounds__(256) void k_gemm(float* __restrict__ agg,
                                              const float* __restrict__ hself,
                                              const float* __restrict__ stats_in,
                                              const float* __restrict__ gamma_in,
                                              const float* __restrict__ beta_in,
                                              int use_bn,
                                              const float* __restrict__ wl,
                                              const float* __restrict__ lb,
                                              const float* __restrict__ wr,
                                              float* __restrict__ stats_out) {
    __shared__ float wlt[HID * 65];
    __shared__ float wrt[HID * 65];
    __shared__ float rsum[4][64], rsq[4][64];
    int t = threadIdx.x;
    for (int i = t; i < HID * HID; i += 256) {
        int j = i >> 6, k = i & 63;
        wlt[k * 65 + j] = wl[i];
        wrt[k * 65 + j] = wr[i];
    }
    __syncthreads();
    int wave = (blockIdx.x * 256 + t) >> 6;
    int lane = t & 63;
    int n0 = wave * 8;

    float sc = 1.f, sh = 0.f;
    if (use_bn) {
        float mu  = stats_in[lane] * INV_N;
        float var = stats_in[HID + lane] * INV_N - mu * mu;
        sc = gamma_in[lane] * rsqrtf(var + BN_EPS);
        sh = beta_in[lane] - mu * sc;
    }

    float av[8], hr[8], acc[8];
#pragma unroll
    for (int m = 0; m < 8; m++) {
        int n = n0 + m;
        bool ok = (n < N_NODES);
        av[m] = ok ? agg[(size_t)n * HID + lane] : 0.f;
        float raw = ok ? hself[(size_t)n * HID + lane] : 0.f;
        hr[m] = use_bn ? fmaxf(raw * sc + sh, 0.f) : raw;
        acc[m] = lb[lane];
    }
#pragma unroll
    for (int k = 0; k < 64; k++) {
        float wlv = wlt[k * 65 + lane];
        float wrv = wrt[k * 65 + lane];
#pragma unroll
        for (int m = 0; m < 8; m++) {
            acc[m] += bcast(av[m], k) * wlv;
            acc[m] += bcast(hr[m], k) * wrv;
        }
    }
    float psum = 0.f, psq = 0.f;
#pragma unroll
    for (int m = 0; m < 8; m++) {
        int n = n0 + m;
        if (n < N_NODES) {
            agg[(size_t)n * HID + lane] = acc[m];   // in-place: pre over agg
            psum += acc[m];
            psq  += acc[m] * acc[m];
        }
    }
    int w = t >> 6;
    rsum[w][lane] = psum;
    rsq[w][lane]  = psq;
    __syncthreads();
    if (w == 0) {
        float s = rsum[0][lane] + rsum[1][lane] + rsum[2][lane] + rsum[3][lane];
        float q = rsq[0][lane]  + rsq[1][lane]  + rsq[2][lane]  + rsq[3][lane];
        atomicAdd(&stats_out[lane], s);
        atomicAdd(&stats_out[HID + lane], q);
    }
}

// ---------- fc2 + log_softmax (reads pre2 through BN+ReLU) ----------
__global__ __launch_bounds__(256) void k_fc2(const float* __restrict__ h,
                                             const float* __restrict__ stats_in,
                                             const float* __restrict__ gamma_in,
                                             const float* __restrict__ beta_in,
                                             const float* __restrict__ w2,
                                             const float* __restrict__ b2,
                                             float* __restrict__ out) {
    __shared__ float w[CLS * HID];
    int t = threadIdx.x;
    for (int i = t; i < CLS * HID; i += 256) w[i] = w2[i];
    __syncthreads();
    int n = (blockIdx.x * 256 + t) >> 6;
    int lane = t & 63;
    if (n >= N_NODES) return;
    float mu  = stats_in[lane] * INV_N;
    float var = stats_in[HID + lane] * INV_N - mu * mu;
    float sc = gamma_in[lane] * rsqrtf(var + BN_EPS);
    float sh = beta_in[lane] - mu * sc;
    float hv = fmaxf(h[(size_t)n * HID + lane] * sc + sh, 0.f);
    float logit[CLS];
#pragma unroll
    for (int j = 0; j < CLS; j++) {
        float p = hv * w[j * HID + lane];
#pragma unroll
        for (int off = 32; off > 0; off >>= 1) p += __shfl_xor(p, off);
        logit[j] = p + b2[j];
    }
    float mx = logit[0];
#pragma unroll
    for (int j = 1; j < CLS; j++) mx = fmaxf(mx, logit[j]);
    float se = 0.f;
#pragma unroll
    for (int j = 0; j < CLS; j++) se += __expf(logit[j] - mx);
    float lse = mx + __logf(se);
    if (lane < CLS) {
        float v = logit[0];
#pragma unroll
        for (int j = 1; j < CLS; j++) v = (lane == j) ? logit[j] : v;
        out[(size_t)n * CLS + lane] = v - lse;
    }
}

extern "C" void kernel_launch(void* const* d_in, const int* in_sizes, int n_in,
                              void* d_out, int out_size, void* d_ws, size_t ws_size,
                              hipStream_t stream) {
    const float* x        = (const float*)d_in[0];
    const int*   ei       = (const int*)d_in[1];     // int32: [2, E] flat
    const float* fc1_w    = (const float*)d_in[2];
    const float* fc1_b    = (const float*)d_in[3];
    const float* lin_l_w  = (const float*)d_in[4];
    const float* lin_l_b  = (const float*)d_in[5];
    const float* lin_r_w  = (const float*)d_in[6];
    const float* bn_gamma = (const float*)d_in[7];
    const float* bn_beta  = (const float*)d_in[8];
    const float* fc2_w    = (const float*)d_in[9];
    const float* fc2_b    = (const float*)d_in[10];
    float* out = (float*)d_out;

    char* p = (char*)d_ws;
    float* bufA    = (float*)p; p += (size_t)N_NODES * HID * 4;   // fc1 out / pre1
    float* bufB    = (float*)p; p += (size_t)N_NODES * HID * 4;   // agg/pre0 / agg2/pre2
    int*   counts  = (int*)p;   p += (size_t)N_NODES * 4;
    int*   offsets = (int*)p;   p += (size_t)(N_NODES + 1) * 4;
    int*   cursor  = (int*)p;   p += (size_t)N_NODES * 4;
    int*   ssrc    = (int*)p;   p += (size_t)N_EDGES * 4;
    float* inv_deg = (float*)p; p += (size_t)N_NODES * 4;
    float* stats   = (float*)p; p += (size_t)NLAYER * 2 * HID * 4; // [l][2][64]

    hipMemsetAsync(counts, 0, (size_t)N_NODES * 4, stream);
    hipMemsetAsync(stats, 0, (size_t)NLAYER * 2 * HID * 4, stream);
    k_count  <<<(N_EDGES + 255) / 256, 256, 0, stream>>>(ei, counts);
    k_scan   <<<1, 1024, 0, stream>>>(counts, offsets, cursor, inv_deg);
    k_scatter<<<(N_EDGES + 255) / 256, 256, 0, stream>>>(ei, cursor, ssrc);
    k_fc1    <<<3125, 256, 0, stream>>>(x, fc1_w, fc1_b, bufA);

    const int AGG_GRID  = (N_NODES + 3) / 4;       // 1 node per wave, 4 waves/block
    const int GEMM_GRID = (N_NODES + 31) / 32;     // 8 nodes per wave

    float* hin = bufA;   // current layer input (raw; use_bn says how to read)
    float* buf = bufB;   // scratch for agg -> pre (in place)
    for (int l = 0; l < NLAYER; l++) {
        int use_bn = (l > 0);
        const float* st_in = (l > 0) ? stats + (size_t)(l - 1) * 2 * HID : stats;
        const float* ga_in = bn_gamma + (size_t)(l > 0 ? l - 1 : 0) * HID;
        const float* be_in = bn_beta  + (size_t)(l > 0 ? l - 1 : 0) * HID;
        k_agg<<<AGG_GRID, 256, 0, stream>>>(hin, offsets, ssrc, inv_deg,
                                            st_in, ga_in, be_in, use_bn, buf);
        k_gemm<<<GEMM_GRID, 256, 0, stream>>>(buf, hin, st_in, ga_in, be_in, use_bn,
                                              lin_l_w + (size_t)l * HID * HID,
                                              lin_l_b + (size_t)l * HID,
                                              lin_r_w + (size_t)l * HID * HID,
                                              stats + (size_t)l * 2 * HID);
        // swap: next layer's input is this layer's pre (in buf)
        float* tmp = hin; hin = buf; buf = tmp;
    }
    k_fc2<<<25000, 256, 0, stream>>>(hin, stats + (size_t)2 * 2 * HID,
                                     bn_gamma + (size_t)2 * HID, bn_beta + (size_t)2 * HID,
                                     fc2_w, fc2_b, out);
}

// Round 5
// 1039.985 us; speedup vs baseline: 2.4150x; 1.2666x over previous
//
#include <hip/hip_runtime.h>

#define N_NODES 100000
#define N_EDGES 1600000
#define IN_DIM  128
#define HID     64
#define CLS     10
#define NLAYER  3
#define BN_EPS  1e-5f
#define INV_N   (1.0f / N_NODES)

__device__ __forceinline__ float bcast(float v, int lane) {
    return __uint_as_float(__builtin_amdgcn_readlane(__float_as_uint(v), lane));
}

__device__ __forceinline__ int clampi(int v, int lo, int hi) {
    return v < lo ? lo : (v > hi ? hi : v);
}

// ---------- CSR build ----------
__global__ void k_count(const int* __restrict__ ei, int* __restrict__ counts) {
    int e = blockIdx.x * blockDim.x + threadIdx.x;
    if (e < N_EDGES) {
        int d = clampi(ei[N_EDGES + e], 0, N_NODES - 1);   // dst row
        atomicAdd(&counts[d], 1);
    }
}

// Assign each node a private contiguous range [start, start+count) via
// block-aggregated atomic on a global cursor. No ordered prefix scan needed.
__global__ __launch_bounds__(256) void k_assign(const int* __restrict__ counts,
                                                int* __restrict__ gcursor,
                                                int* __restrict__ start,
                                                int* __restrict__ cursor,
                                                float* __restrict__ inv_deg) {
    __shared__ int wbase[4];
    int t = threadIdx.x;
    int n = blockIdx.x * 256 + t;
    int lane = t & 63;
    int w = t >> 6;
    int c = (n < N_NODES) ? counts[n] : 0;
    // inclusive scan within wave
    int pref = c;
#pragma unroll
    for (int off = 1; off < 64; off <<= 1) {
        int v = __shfl_up(pref, off);
        if (lane >= off) pref += v;
    }
    if (lane == 63) wbase[w] = pref;   // wave total
    __syncthreads();
    if (t == 0) {
        int s0 = wbase[0], s1 = wbase[1], s2 = wbase[2], s3 = wbase[3];
        int b = atomicAdd(gcursor, s0 + s1 + s2 + s3);
        wbase[0] = b; wbase[1] = b + s0; wbase[2] = b + s0 + s1; wbase[3] = b + s0 + s1 + s2;
    }
    __syncthreads();
    if (n < N_NODES) {
        int st = wbase[w] + (pref - c);
        start[n]  = st;
        cursor[n] = st;
        inv_deg[n] = (c > 0) ? 1.0f / (float)c : 0.0f;
    }
}

__global__ void k_scatter(const int* __restrict__ ei, int* __restrict__ cursor,
                          int* __restrict__ ssrc) {
    int e = blockIdx.x * blockDim.x + threadIdx.x;
    if (e < N_EDGES) {
        int d = clampi(ei[N_EDGES + e], 0, N_NODES - 1);
        int s = clampi(ei[e],           0, N_NODES - 1);
        int pos = atomicAdd(&cursor[d], 1);
        if (pos >= 0 && pos < N_EDGES) ssrc[pos] = s;
    }
}

// ---------- fc1: h = relu(x @ W1^T + b1), x [N,128] -> h [N,64] ----------
__global__ __launch_bounds__(256) void k_fc1(const float* __restrict__ x,
                                             const float* __restrict__ w,
                                             const float* __restrict__ b,
                                             float* __restrict__ h) {
    __shared__ float wt[IN_DIM * 65];   // wt[k*65+j] = w[j*128+k], padded stride
    int t = threadIdx.x;
    for (int i = t; i < IN_DIM * HID; i += 256) {
        int j = i >> 7, k = i & 127;
        wt[k * 65 + j] = w[i];
    }
    __syncthreads();
    int wave = (blockIdx.x * 256 + t) >> 6;
    int lane = t & 63;
    int n0 = wave * 8;
    float xa[8], xb[8], acc[8];
#pragma unroll
    for (int m = 0; m < 8; m++) {
        int n = n0 + m;
        bool ok = (n < N_NODES);
        xa[m] = ok ? x[(size_t)n * IN_DIM + lane]      : 0.f;
        xb[m] = ok ? x[(size_t)n * IN_DIM + 64 + lane] : 0.f;
        acc[m] = b[lane];
    }
#pragma unroll
    for (int k = 0; k < 64; k++) {
        float wv = wt[k * 65 + lane];
#pragma unroll
        for (int m = 0; m < 8; m++) acc[m] += bcast(xa[m], k) * wv;
    }
#pragma unroll
    for (int k = 0; k < 64; k++) {
        float wv = wt[(64 + k) * 65 + lane];
#pragma unroll
        for (int m = 0; m < 8; m++) acc[m] += bcast(xb[m], k) * wv;
    }
#pragma unroll
    for (int m = 0; m < 8; m++) {
        int n = n0 + m;
        if (n < N_NODES) h[(size_t)n * HID + lane] = fmaxf(acc[m], 0.f);
    }
}

// ---------- k_agg: agg[n] = mean_{u in nbrs(n)} f(hin[u]) ----------
// f = BN+ReLU (from raw sum/sumsq stats) if use_bn, else identity.
// One wave per node; 4 groups of 16 lanes; lane holds float4 (4 channels).
__global__ __launch_bounds__(256, 6) void k_agg(const float* __restrict__ hin,
                                                const int* __restrict__ start,
                                                const int* __restrict__ counts,
                                                const int* __restrict__ ssrc,
                                                const float* __restrict__ inv_deg,
                                                const float* __restrict__ stats,
                                                const float* __restrict__ gamma,
                                                const float* __restrict__ beta,
                                                int use_bn,
                                                float* __restrict__ aggout) {
    int wave = (blockIdx.x * 256 + threadIdx.x) >> 6;
    int lane = threadIdx.x & 63;
    int g  = lane >> 4;       // group 0..3
    int gl = lane & 15;       // lane within group; channels gl*4 .. gl*4+3
    int n = wave;
    if (n >= N_NODES) return;

    float sc0 = 1.f, sc1 = 1.f, sc2 = 1.f, sc3 = 1.f;
    float sh0 = 0.f, sh1 = 0.f, sh2 = 0.f, sh3 = 0.f;
    if (use_bn) {
        int c = gl * 4;
        float4 s1 = *(const float4*)&stats[c];
        float4 s2 = *(const float4*)&stats[HID + c];
        float4 ga = *(const float4*)&gamma[c];
        float4 be = *(const float4*)&beta[c];
        float mu, var;
        mu = s1.x * INV_N; var = s2.x * INV_N - mu * mu; sc0 = ga.x * rsqrtf(var + BN_EPS); sh0 = be.x - mu * sc0;
        mu = s1.y * INV_N; var = s2.y * INV_N - mu * mu; sc1 = ga.y * rsqrtf(var + BN_EPS); sh1 = be.y - mu * sc1;
        mu = s1.z * INV_N; var = s2.z * INV_N - mu * mu; sc2 = ga.z * rsqrtf(var + BN_EPS); sh2 = be.z - mu * sc2;
        mu = s1.w * INV_N; var = s2.w * INV_N - mu * mu; sc3 = ga.w * rsqrtf(var + BN_EPS); sh3 = be.w - mu * sc3;
    }

    int s = start[n], cnt = counts[n];
    int e = s + cnt;
    float ax = 0.f, ay = 0.f, az = 0.f, aw = 0.f;
    int i = s + g;

#define GATHER1(u) do { \
        const float4 v = *(const float4*)&hin[(size_t)(u) * HID + gl * 4]; \
        if (use_bn) { \
            ax += fmaxf(v.x * sc0 + sh0, 0.f); \
            ay += fmaxf(v.y * sc1 + sh1, 0.f); \
            az += fmaxf(v.z * sc2 + sh2, 0.f); \
            aw += fmaxf(v.w * sc3 + sh3, 0.f); \
        } else { ax += v.x; ay += v.y; az += v.z; aw += v.w; } \
    } while (0)

    for (; i + 12 < e; i += 16) {
        int u0 = ssrc[i], u1 = ssrc[i + 4], u2 = ssrc[i + 8], u3 = ssrc[i + 12];
        const float4 v0 = *(const float4*)&hin[(size_t)u0 * HID + gl * 4];
        const float4 v1 = *(const float4*)&hin[(size_t)u1 * HID + gl * 4];
        const float4 v2 = *(const float4*)&hin[(size_t)u2 * HID + gl * 4];
        const float4 v3 = *(const float4*)&hin[(size_t)u3 * HID + gl * 4];
        if (use_bn) {
            ax += fmaxf(v0.x * sc0 + sh0, 0.f) + fmaxf(v1.x * sc0 + sh0, 0.f)
                + fmaxf(v2.x * sc0 + sh0, 0.f) + fmaxf(v3.x * sc0 + sh0, 0.f);
            ay += fmaxf(v0.y * sc1 + sh1, 0.f) + fmaxf(v1.y * sc1 + sh1, 0.f)
                + fmaxf(v2.y * sc1 + sh1, 0.f) + fmaxf(v3.y * sc1 + sh1, 0.f);
            az += fmaxf(v0.z * sc2 + sh2, 0.f) + fmaxf(v1.z * sc2 + sh2, 0.f)
                + fmaxf(v2.z * sc2 + sh2, 0.f) + fmaxf(v3.z * sc2 + sh2, 0.f);
            aw += fmaxf(v0.w * sc3 + sh3, 0.f) + fmaxf(v1.w * sc3 + sh3, 0.f)
                + fmaxf(v2.w * sc3 + sh3, 0.f) + fmaxf(v3.w * sc3 + sh3, 0.f);
        } else {
            ax += (v0.x + v1.x) + (v2.x + v3.x);
            ay += (v0.y + v1.y) + (v2.y + v3.y);
            az += (v0.z + v1.z) + (v2.z + v3.z);
            aw += (v0.w + v1.w) + (v2.w + v3.w);
        }
    }
    for (; i < e; i += 4) {
        int u = ssrc[i];
        GATHER1(u);
    }
#undef GATHER1

    // cross-group reduce (lanes gl, gl+16, gl+32, gl+48)
#pragma unroll
    for (int st = 16; st <= 32; st <<= 1) {
        ax += __shfl_xor(ax, st);
        ay += __shfl_xor(ay, st);
        az += __shfl_xor(az, st);
        aw += __shfl_xor(aw, st);
    }
    if (g == 0) {
        float id = inv_deg[n];
        float4 r; r.x = ax * id; r.y = ay * id; r.z = az * id; r.w = aw * id;
        *(float4*)&aggout[(size_t)n * HID + gl * 4] = r;
    }
}

// ---------- k_gemm: pre[n] = Wl*agg[n] + bl + Wr*f(hself[n]); BN stats of pre ----------
__global__ __launch_bounds__(256) void k_gemm(float* __restrict__ agg,
                                              const float* __restrict__ hself,
                                              const float* __restrict__ stats_in,
                                              const float* __restrict__ gamma_in,
                                              const float* __restrict__ beta_in,
                                              int use_bn,
                                              const float* __restrict__ wl,
                                              const float* __restrict__ lb,
                                              const float* __restrict__ wr,
                                              float* __restrict__ stats_out) {
    __shared__ float wlt[HID * 65];
    __shared__ float wrt[HID * 65];
    __shared__ float rsum[4][64], rsq[4][64];
    int t = threadIdx.x;
    for (int i = t; i < HID * HID; i += 256) {
        int j = i >> 6, k = i & 63;
        wlt[k * 65 + j] = wl[i];
        wrt[k * 65 + j] = wr[i];
    }
    __syncthreads();
    int wave = (blockIdx.x * 256 + t) >> 6;
    int lane = t & 63;
    int n0 = wave * 8;

    float sc = 1.f, sh = 0.f;
    if (use_bn) {
        float mu  = stats_in[lane] * INV_N;
        float var = stats_in[HID + lane] * INV_N - mu * mu;
        sc = gamma_in[lane] * rsqrtf(var + BN_EPS);
        sh = beta_in[lane] - mu * sc;
    }

    float av[8], hr[8], acc[8];
#pragma unroll
    for (int m = 0; m < 8; m++) {
        int n = n0 + m;
        bool ok = (n < N_NODES);
        av[m] = ok ? agg[(size_t)n * HID + lane] : 0.f;
        float raw = ok ? hself[(size_t)n * HID + lane] : 0.f;
        hr[m] = use_bn ? fmaxf(raw * sc + sh, 0.f) : raw;
        acc[m] = lb[lane];
    }
#pragma unroll
    for (int k = 0; k < 64; k++) {
        float wlv = wlt[k * 65 + lane];
        float wrv = wrt[k * 65 + lane];
#pragma unroll
        for (int m = 0; m < 8; m++) {
            acc[m] += bcast(av[m], k) * wlv;
            acc[m] += bcast(hr[m], k) * wrv;
        }
    }
    float psum = 0.f, psq = 0.f;
#pragma unroll
    for (int m = 0; m < 8; m++) {
        int n = n0 + m;
        if (n < N_NODES) {
            agg[(size_t)n * HID + lane] = acc[m];   // in-place: pre over agg
            psum += acc[m];
            psq  += acc[m] * acc[m];
        }
    }
    int w = t >> 6;
    rsum[w][lane] = psum;
    rsq[w][lane]  = psq;
    __syncthreads();
    if (w == 0) {
        float s = rsum[0][lane] + rsum[1][lane] + rsum[2][lane] + rsum[3][lane];
        float q = rsq[0][lane]  + rsq[1][lane]  + rsq[2][lane]  + rsq[3][lane];
        atomicAdd(&stats_out[lane], s);
        atomicAdd(&stats_out[HID + lane], q);
    }
}

// ---------- fc2 + log_softmax (reads pre2 through BN+ReLU) ----------
__global__ __launch_bounds__(256) void k_fc2(const float* __restrict__ h,
                                             const float* __restrict__ stats_in,
                                             const float* __restrict__ gamma_in,
                                             const float* __restrict__ beta_in,
                                             const float* __restrict__ w2,
                                             const float* __restrict__ b2,
                                             float* __restrict__ out) {
    __shared__ float w[CLS * HID];
    int t = threadIdx.x;
    for (int i = t; i < CLS * HID; i += 256) w[i] = w2[i];
    __syncthreads();
    int n = (blockIdx.x * 256 + t) >> 6;
    int lane = t & 63;
    if (n >= N_NODES) return;
    float mu  = stats_in[lane] * INV_N;
    float var = stats_in[HID + lane] * INV_N - mu * mu;
    float sc = gamma_in[lane] * rsqrtf(var + BN_EPS);
    float sh = beta_in[lane] - mu * sc;
    float hv = fmaxf(h[(size_t)n * HID + lane] * sc + sh, 0.f);
    float logit[CLS];
#pragma unroll
    for (int j = 0; j < CLS; j++) {
        float p = hv * w[j * HID + lane];
#pragma unroll
        for (int off = 32; off > 0; off >>= 1) p += __shfl_xor(p, off);
        logit[j] = p + b2[j];
    }
    float mx = logit[0];
#pragma unroll
    for (int j = 1; j < CLS; j++) mx = fmaxf(mx, logit[j]);
    float se = 0.f;
#pragma unroll
    for (int j = 0; j < CLS; j++) se += __expf(logit[j] - mx);
    float lse = mx + __logf(se);
    if (lane < CLS) {
        float v = logit[0];
#pragma unroll
        for (int j = 1; j < CLS; j++) v = (lane == j) ? logit[j] : v;
        out[(size_t)n * CLS + lane] = v - lse;
    }
}

extern "C" void kernel_launch(void* const* d_in, const int* in_sizes, int n_in,
                              void* d_out, int out_size, void* d_ws, size_t ws_size,
                              hipStream_t stream) {
    const float* x        = (const float*)d_in[0];
    const int*   ei       = (const int*)d_in[1];     // int32: [2, E] flat
    const float* fc1_w    = (const float*)d_in[2];
    const float* fc1_b    = (const float*)d_in[3];
    const float* lin_l_w  = (const float*)d_in[4];
    const float* lin_l_b  = (const float*)d_in[5];
    const float* lin_r_w  = (const float*)d_in[6];
    const float* bn_gamma = (const float*)d_in[7];
    const float* bn_beta  = (const float*)d_in[8];
    const float* fc2_w    = (const float*)d_in[9];
    const float* fc2_b    = (const float*)d_in[10];
    float* out = (float*)d_out;

    char* p = (char*)d_ws;
    float* bufA    = (float*)p; p += (size_t)N_NODES * HID * 4;   // fc1 out / pre1
    float* bufB    = (float*)p; p += (size_t)N_NODES * HID * 4;   // agg/pre0 / agg2/pre2
    // --- zeroed region (one memset): counts, gcursor, stats ---
    char*  zbase   = p;
    int*   counts  = (int*)p;   p += (size_t)N_NODES * 4;
    int*   gcursor = (int*)p;   p += 4 * 4;                        // padded
    float* stats   = (float*)p; p += (size_t)NLAYER * 2 * HID * 4; // [l][2][64]
    size_t zbytes  = (size_t)(p - zbase);
    // --- end zeroed region ---
    int*   start   = (int*)p;   p += (size_t)N_NODES * 4;
    int*   cursor  = (int*)p;   p += (size_t)N_NODES * 4;
    int*   ssrc    = (int*)p;   p += (size_t)N_EDGES * 4;
    float* inv_deg = (float*)p; p += (size_t)N_NODES * 4;

    hipMemsetAsync(zbase, 0, zbytes, stream);
    k_count  <<<(N_EDGES + 255) / 256, 256, 0, stream>>>(ei, counts);
    k_assign <<<(N_NODES + 255) / 256, 256, 0, stream>>>(counts, gcursor, start, cursor, inv_deg);
    k_scatter<<<(N_EDGES + 255) / 256, 256, 0, stream>>>(ei, cursor, ssrc);
    k_fc1    <<<3125, 256, 0, stream>>>(x, fc1_w, fc1_b, bufA);

    const int AGG_GRID  = (N_NODES + 3) / 4;       // 1 node per wave, 4 waves/block
    const int GEMM_GRID = (N_NODES + 31) / 32;     // 8 nodes per wave

    float* hin = bufA;   // current layer input (raw; use_bn says how to read)
    float* buf = bufB;   // scratch for agg -> pre (in place)
    for (int l = 0; l < NLAYER; l++) {
        int use_bn = (l > 0);
        const float* st_in = (l > 0) ? stats + (size_t)(l - 1) * 2 * HID : stats;
        const float* ga_in = bn_gamma + (size_t)(l > 0 ? l - 1 : 0) * HID;
        const float* be_in = bn_beta  + (size_t)(l > 0 ? l - 1 : 0) * HID;
        k_agg<<<AGG_GRID, 256, 0, stream>>>(hin, start, counts, ssrc, inv_deg,
                                            st_in, ga_in, be_in, use_bn, buf);
        k_gemm<<<GEMM_GRID, 256, 0, stream>>>(buf, hin, st_in, ga_in, be_in, use_bn,
                                              lin_l_w + (size_t)l * HID * HID,
                                              lin_l_b + (size_t)l * HID,
                                              lin_r_w + (size_t)l * HID * HID,
                                              stats + (size_t)l * 2 * HID);
        float* tmp = hin; hin = buf; buf = tmp;
    }
    k_fc2<<<25000, 256, 0, stream>>>(hin, stats + (size_t)2 * 2 * HID,
                                     bn_gamma + (size_t)2 * HID, bn_beta + (size_t)2 * HID,
                                     fc2_w, fc2_b, out);
}